// Round 2
// baseline (113.808 us; speedup 1.0000x reference)
//
#include <hip/hip_runtime.h>

#define BATCH 64
#define LLEN 65536
#define NW 2047
#define STATS 321
#define NCHUNK 32   // chunks per row; each chunk = 2048 elements, 64 windows

// ---- wave64 sum via DPP (6 VALU adds); returns total (lane-63 value) uniform ----
__device__ __forceinline__ float dppWaveSumBcast(float x) {
    float t;
    t = __int_as_float(__builtin_amdgcn_update_dpp(0, __float_as_int(x), 0x111, 0xf, 0xf, true));  x += t; // row_shr:1
    t = __int_as_float(__builtin_amdgcn_update_dpp(0, __float_as_int(x), 0x112, 0xf, 0xf, true));  x += t; // row_shr:2
    t = __int_as_float(__builtin_amdgcn_update_dpp(0, __float_as_int(x), 0x114, 0xf, 0xf, true));  x += t; // row_shr:4
    t = __int_as_float(__builtin_amdgcn_update_dpp(0, __float_as_int(x), 0x118, 0xf, 0xf, true));  x += t; // row_shr:8
    t = __int_as_float(__builtin_amdgcn_update_dpp(0, __float_as_int(x), 0x142, 0xa, 0xf, false)); x += t; // row_bcast:15
    t = __int_as_float(__builtin_amdgcn_update_dpp(0, __float_as_int(x), 0x143, 0xc, 0xf, false)); x += t; // row_bcast:31
    return __int_as_float(__builtin_amdgcn_readlane(__float_as_int(x), 63));
}

// ---------------- fused front-end: single-pass histogram + windowed entropy ----------------
// grid (NCHUNK, BATCH), 256 threads. Each wave owns 512 contiguous elements e[0..7]
// (+ e[8] = first 64 of the next span for the last odd window).
// Even windows 2j == e[j] exactly (stride 32 => even windows tile the data).
// Odd-window ballots derived scalar-only from neighbor ballots: {B.hi, N.lo}.
// Histogram comes free from even-window match masks via leader election (mbcnt).
// Epilogue: integer atomicAdd directly into per-row hist/ccnt (pre-zeroed by memset).
__global__ __launch_bounds__(256) void front_kernel(const int* __restrict__ x,
                                                    int* __restrict__ hist,
                                                    int* __restrict__ ccnt) {
    __shared__ int lh[256];
    __shared__ int lc[256];
    const int row = blockIdx.y;
    const int c = blockIdx.x;
    const int t = threadIdx.x;
    const int lane = t & 63;
    const int wave = t >> 6;
    lh[t] = 0;
    __syncthreads();

    const int* xr = x + row * LLEN;
    const int eb = c * 2048 + wave * 512;

    int e[9];
#pragma unroll
    for (int j = 0; j < 8; ++j) e[j] = min(max(xr[eb + j * 64 + lane], 0), 255);
    // e[8]: lo-half feeds the last odd window; clamp keeps the final wave in-bounds
    // (that window is the single invalid one and is masked below).
    e[8] = min(max(xr[min(eb + 512, LLEN - 64) + lane], 0), 255);

    const float lv = (lane == 63) ? 8.0f : (float)lane * (8.0f / 63.0f);
    const float T = (6.0f - lv) * 64.0f;
    const int wbase = c * 64 + wave * 16;
    const int xlane = lane ^ 32;

    // ballots of group 0
    unsigned Blo[8], Bhi[8];
#pragma unroll
    for (int k = 0; k < 8; ++k) {
        const unsigned long long b = __ballot(e[0] & (1 << k));
        Blo[k] = (unsigned)b;
        Bhi[k] = (unsigned)(b >> 32);
    }

    int cnt = 0;
#pragma unroll
    for (int j = 0; j < 8; ++j) {
        // ballots of next group (uniform flow: before any divergence)
        unsigned Nlo[8], Nhi[8];
#pragma unroll
        for (int k = 0; k < 8; ++k) {
            const unsigned long long b = __ballot(e[j + 1] & (1 << k));
            Nlo[k] = (unsigned)b;
            Nhi[k] = (unsigned)(b >> 32);
        }
        // odd-window per-lane value: lanes<32 take e[j] hi-half, lanes>=32 take e[j+1] lo-half
        const int srcv = (lane < 32) ? e[j + 1] : e[j];
        const int u = __shfl(srcv, xlane);

        // ---- even window 2j (values e[j], ballots B) ----
        {
            unsigned mlo = 0xffffffffu, mhi = 0xffffffffu;
#pragma unroll
            for (int k = 0; k < 8; ++k) {
                const unsigned s = (unsigned)(((e[j] >> k) & 1) - 1); // 0 if bit set, ~0 if clear
                mlo &= Blo[k] ^ s;
                mhi &= Bhi[k] ^ s;
            }
            const int cc = __popc(mlo) + __popc(mhi);
            const float S = dppWaveSumBcast(__log2f((float)cc));
            cnt += (int)(S >= T);  // even windows are always valid (max w = 2046)
            // histogram: lowest lane of each equal-class adds the class count once
            unsigned below = __builtin_amdgcn_mbcnt_lo(mlo, 0u);
            below = __builtin_amdgcn_mbcnt_hi(mhi, below);
            if (below == 0u) atomicAdd(&lh[e[j]], cc);
        }

        // ---- odd window 2j+1 (ballots {B.hi, N.lo}, values u) ----
        {
            unsigned mlo = 0xffffffffu, mhi = 0xffffffffu;
#pragma unroll
            for (int k = 0; k < 8; ++k) {
                const unsigned s = (unsigned)(((u >> k) & 1) - 1);
                mlo &= Bhi[k] ^ s;
                mhi &= Nlo[k] ^ s;
            }
            const int cc = __popc(mlo) + __popc(mhi);
            const float S = dppWaveSumBcast(__log2f((float)cc));
            cnt += (int)((S >= T) && (wbase + 2 * j + 1 < NW));
        }

        // rotate ballots (register rename after full unroll; zero cost)
#pragma unroll
        for (int k = 0; k < 8; ++k) { Blo[k] = Nlo[k]; Bhi[k] = Nhi[k]; }
    }
    lc[t] = cnt;
    __syncthreads();

    atomicAdd(&hist[row * 256 + t], lh[t]);
    if (t < 64)
        atomicAdd(&ccnt[row * 64 + t], lc[t] + lc[64 + t] + lc[128 + t] + lc[192 + t]);
}

// ---------------- feats + MLP layer 1: 4 rows/block, [321] @ W1[321,512] + b1 ----------------
// grid (8 colblk, 16 rowgrp), 256 thr. Wave w = k-group w (84 k's); lane = col.
__global__ __launch_bounds__(256) void gemm1_kernel(
    const int* __restrict__ hist, const int* __restrict__ ccnt,
    const float* __restrict__ W, const float* __restrict__ b,
    float* __restrict__ out) {
    __shared__ float feats[4][324];   // 324: pad, 16B-aligned rows
    __shared__ float reds[4][4];
    __shared__ float part[4][4][64];
    const int t = threadIdx.x;
    const int lane = t & 63;
    const int wave = t >> 6;
    const int rb = blockIdx.y * 4;

    // feats: normalized hist + global entropy (same per-row reduce order as verified kernel)
#pragma unroll
    for (int r = 0; r < 4; ++r) {
        const int h = hist[(rb + r) * 256 + t];
        const float p = (float)h * (1.0f / 65536.0f);
        feats[r][t] = p;
        const float term = -p * log2f(p + 1e-10f);  // p==0 -> 0, matches ref
        const float s = dppWaveSumBcast(term);
        if (lane == 0) reds[r][wave] = s;
    }
    {
        const int r = t >> 6, lv = t & 63;
        feats[r][257 + lv] = (float)ccnt[(rb + r) * 64 + lv] * (1.0f / 2047.0f);
    }
    __syncthreads();
    if (t < 4) feats[t][256] = reds[t][0] + reds[t][1] + reds[t][2] + reds[t][3];
    __syncthreads();

    const int colbase = blockIdx.x * 64;
    const float* Wc = W + colbase + lane;
    float acc0 = 0.f, acc1 = 0.f, acc2 = 0.f, acc3 = 0.f;
    const int klo = wave * 84;
    const int khi = min(klo + 84, STATS);
    int k = klo;
    for (; k + 4 <= khi; k += 4) {
        const float4 a0 = *(const float4*)&feats[0][k];
        const float4 a1 = *(const float4*)&feats[1][k];
        const float4 a2 = *(const float4*)&feats[2][k];
        const float4 a3 = *(const float4*)&feats[3][k];
        const float w0 = Wc[(k + 0) * 512];
        const float w1 = Wc[(k + 1) * 512];
        const float w2 = Wc[(k + 2) * 512];
        const float w3 = Wc[(k + 3) * 512];
        acc0 = fmaf(a0.x, w0, acc0); acc0 = fmaf(a0.y, w1, acc0);
        acc0 = fmaf(a0.z, w2, acc0); acc0 = fmaf(a0.w, w3, acc0);
        acc1 = fmaf(a1.x, w0, acc1); acc1 = fmaf(a1.y, w1, acc1);
        acc1 = fmaf(a1.z, w2, acc1); acc1 = fmaf(a1.w, w3, acc1);
        acc2 = fmaf(a2.x, w0, acc2); acc2 = fmaf(a2.y, w1, acc2);
        acc2 = fmaf(a2.z, w2, acc2); acc2 = fmaf(a2.w, w3, acc2);
        acc3 = fmaf(a3.x, w0, acc3); acc3 = fmaf(a3.y, w1, acc3);
        acc3 = fmaf(a3.z, w2, acc3); acc3 = fmaf(a3.w, w3, acc3);
    }
    for (; k < khi; ++k) {  // tail (kg==3 only: k=320)
        const float w = Wc[k * 512];
        acc0 = fmaf(feats[0][k], w, acc0);
        acc1 = fmaf(feats[1][k], w, acc1);
        acc2 = fmaf(feats[2][k], w, acc2);
        acc3 = fmaf(feats[3][k], w, acc3);
    }
    part[wave][0][lane] = acc0;
    part[wave][1][lane] = acc1;
    part[wave][2][lane] = acc2;
    part[wave][3][lane] = acc3;
    __syncthreads();
    {
        const int r2 = t >> 6, c2 = t & 63;
        float o = b[colbase + c2];
#pragma unroll
        for (int gI = 0; gI < 4; ++gI) o += part[gI][r2][c2];
        out[(rb + r2) * 512 + colbase + c2] = o;
    }
}

// ---------------- MLP layers 2/3: 4 rows/block, LN(raw)+ReLU then @ W + b ----------------
// grid (NOUT/COLS? -> 8, 16 rowgrp), 256 thr. LN reduce order bit-identical to verified kernel.
template <int NOUT, int COLS>
__global__ __launch_bounds__(256) void gemm_ln_kernel(
    const float* __restrict__ raw, const float* __restrict__ g,
    const float* __restrict__ be, const float* __restrict__ W,
    const float* __restrict__ b, float* __restrict__ out) {
    constexpr int KG = 256 / COLS;  // 4 (layer2) / 8 (layer3)
    constexpr int KI = 512 / KG;    // 128 / 64
    __shared__ float sa[4][512];
    __shared__ float reds[4][4];
    __shared__ float redq[4][4];
    __shared__ float part[KG][4][COLS];
    const int t = threadIdx.x;
    const int lane = t & 63;
    const int wave = t >> 6;
    const int rb = blockIdx.y * 4;

    const float gv1 = g[t], gv2 = g[t + 256];
    const float bv1 = be[t], bv2 = be[t + 256];
    float vr1[4], vr2[4];
#pragma unroll
    for (int r = 0; r < 4; ++r) {
        vr1[r] = raw[(rb + r) * 512 + t];
        vr2[r] = raw[(rb + r) * 512 + 256 + t];
        const float s = dppWaveSumBcast(vr1[r] + vr2[r]);
        const float q = dppWaveSumBcast(vr1[r] * vr1[r] + vr2[r] * vr2[r]);
        if (lane == 0) { reds[r][wave] = s; redq[r][wave] = q; }
    }
    __syncthreads();
#pragma unroll
    for (int r = 0; r < 4; ++r) {
        const float mu = (reds[r][0] + reds[r][1] + reds[r][2] + reds[r][3]) * (1.0f / 512.0f);
        const float var = (redq[r][0] + redq[r][1] + redq[r][2] + redq[r][3]) * (1.0f / 512.0f) - mu * mu;
        const float rs = rsqrtf(var + 1e-5f);
        sa[r][t] = fmaxf((vr1[r] - mu) * rs * gv1 + bv1, 0.0f);
        sa[r][t + 256] = fmaxf((vr2[r] - mu) * rs * gv2 + bv2, 0.0f);
    }
    __syncthreads();

    const int col = t % COLS;
    const int kg = t / COLS;
    const int colbase = blockIdx.x * COLS;
    const float* Wc = W + colbase + col;
    float acc0 = 0.f, acc1 = 0.f, acc2 = 0.f, acc3 = 0.f;
    const int klo = kg * KI;
    for (int k = klo; k < klo + KI; k += 4) {
        const float4 a0 = *(const float4*)&sa[0][k];
        const float4 a1 = *(const float4*)&sa[1][k];
        const float4 a2 = *(const float4*)&sa[2][k];
        const float4 a3 = *(const float4*)&sa[3][k];
        const float w0 = Wc[(k + 0) * NOUT];
        const float w1 = Wc[(k + 1) * NOUT];
        const float w2 = Wc[(k + 2) * NOUT];
        const float w3 = Wc[(k + 3) * NOUT];
        acc0 = fmaf(a0.x, w0, acc0); acc0 = fmaf(a0.y, w1, acc0);
        acc0 = fmaf(a0.z, w2, acc0); acc0 = fmaf(a0.w, w3, acc0);
        acc1 = fmaf(a1.x, w0, acc1); acc1 = fmaf(a1.y, w1, acc1);
        acc1 = fmaf(a1.z, w2, acc1); acc1 = fmaf(a1.w, w3, acc1);
        acc2 = fmaf(a2.x, w0, acc2); acc2 = fmaf(a2.y, w1, acc2);
        acc2 = fmaf(a2.z, w2, acc2); acc2 = fmaf(a2.w, w3, acc2);
        acc3 = fmaf(a3.x, w0, acc3); acc3 = fmaf(a3.y, w1, acc3);
        acc3 = fmaf(a3.z, w2, acc3); acc3 = fmaf(a3.w, w3, acc3);
    }
    part[kg][0][col] = acc0;
    part[kg][1][col] = acc1;
    part[kg][2][col] = acc2;
    part[kg][3][col] = acc3;
    __syncthreads();
    if (t < 4 * COLS) {
        const int r2 = t / COLS, c2 = t % COLS;
        float o = b[colbase + c2];
#pragma unroll
        for (int gI = 0; gI < KG; ++gI) o += part[gI][r2][c2];
        out[(rb + r2) * NOUT + colbase + c2] = o;
    }
}

extern "C" void kernel_launch(void* const* d_in, const int* in_sizes, int n_in,
                              void* d_out, int out_size, void* d_ws, size_t ws_size,
                              hipStream_t stream) {
    const int* x = (const int*)d_in[0];
    const float* W1 = (const float*)d_in[1];
    const float* b1 = (const float*)d_in[2];
    const float* g1 = (const float*)d_in[3];
    const float* be1 = (const float*)d_in[4];
    const float* W2 = (const float*)d_in[5];
    const float* b2 = (const float*)d_in[6];
    const float* g2 = (const float*)d_in[7];
    const float* be2 = (const float*)d_in[8];
    const float* W3 = (const float*)d_in[9];
    const float* b3 = (const float*)d_in[10];
    float* out = (float*)d_out;

    char* ws = (char*)d_ws;
    int* hist = (int*)ws;                   // 64*256*4 = 64 KiB
    int* ccnt = (int*)(ws + 65536);         // 64*64*4  = 16 KiB
    float* raw1 = (float*)(ws + 81920);     // 64*512*4 = 128 KiB
    float* raw2 = (float*)(ws + 212992);    // 64*512*4 = 128 KiB

    hipMemsetAsync(ws, 0, 81920, stream);   // zero hist+ccnt for atomic accumulation
    front_kernel<<<dim3(NCHUNK, BATCH), 256, 0, stream>>>(x, hist, ccnt);
    gemm1_kernel<<<dim3(8, 16), 256, 0, stream>>>(hist, ccnt, W1, b1, raw1);
    gemm_ln_kernel<512, 64><<<dim3(8, 16), 256, 0, stream>>>(raw1, g1, be1, W2, b2, raw2);
    gemm_ln_kernel<256, 32><<<dim3(8, 16), 256, 0, stream>>>(raw2, g2, be2, W3, b3, out);
}